// Round 15
// baseline (211.920 us; speedup 1.0000x reference)
//
#include <hip/hip_runtime.h>
#include <math.h>

// ReaReaConv via linearity factorization + two-level owner-scatter binning:
//   u[b,t,:] = dis_t^2 * x[b,t,:] + sum_e norm_e*(1-f_be)*x[b,src_e,:]
//   v[b,t,:] =                      sum_e norm_e*   f_be *x[b,src_e,:]
//   out      = bias + [u v] @ [Wc;Wd]^T   (MFMA, M=BN,K=128,N=64)
// Pipeline: memset(padded cursors) -> K1{binA1 + dedicated convert blocks}
// -> K2{binA2} -> K3a/b/c{aggregate, THREE ~20us dispatches} -> K4{gemm}.
// R15 is an attribution round: with the largest aggregate part ~21us, the
// profiler's top-5 must surface the true durations of binA1_convert / binA2
// / gemm (every estimate-driven poke at them was neutral; R10's split was
// the session's most productive move). All non-aggregate kernels are
// byte-identical to the 202.6us R14 build.
// nodeinfo: {rsqrt(deg+1),flux0,flux1,deg<<21|rowstart}, rowstart<2^21.

constexpr int C = 64;
constexpr int CNB = 128;    // nodes per coarse bucket
constexpr int CCAP = 5120;  // entries per bucket (Poisson mean 4096, +16 sigma)
constexpr int CHUNK = 4096; // edges per binA1 block (391 blocks)
constexpr int CPAD = 16;    // cursor padding: one cursor per 64B line
constexpr int NCV = 1024;   // dedicated convert blocks in fused K1

typedef short short8 __attribute__((ext_vector_type(8)));
typedef float f32x4 __attribute__((ext_vector_type(4)));

__device__ __forceinline__ unsigned pack_bf16x2(float a, float b) {
    unsigned ua = __float_as_uint(a);
    ua = (ua + 0x7fffu + ((ua >> 16) & 1u)) >> 16;  // RNE
    unsigned ub = __float_as_uint(b);
    ub = (ub + 0x7fffu + ((ub >> 16) & 1u)) >> 16;
    return ua | (ub << 16);
}
__device__ __forceinline__ float bflo(unsigned p) { return __uint_as_float(p << 16); }
__device__ __forceinline__ float bfhi(unsigned p) { return __uint_as_float(p & 0xffff0000u); }

// ---- K1: block-specialized fusion.
// blocks [0, nBin): coarse binning into 391 buckets of 128 nodes (per-block
//   LDS histogram -> one padded-cursor atomic per (block,bucket) -> 8B
//   entries in ~10-entry runs).
// blocks [nBin, nBin+NCV): x -> packed bf16x2 grid-stride convert.
__global__ __launch_bounds__(512) void binA1_convert_kernel(
    const int* __restrict__ src, const int* __restrict__ tgt,
    const float* __restrict__ fdo, int* __restrict__ coarseCursor,
    unsigned long long* __restrict__ slab, int E, int ncoarse, int nBin,
    const float* __restrict__ x, unsigned* __restrict__ xb2, int nwords) {
    const int tid = threadIdx.x;
    if (blockIdx.x >= nBin) {
        // ---- convert specialization: ~160 idle CUs during binning
        int gid = (blockIdx.x - nBin) * 512 + tid;
        const int stride = NCV * 512;
        const float2* x2 = (const float2*)x;
        for (int w = gid; w < nwords; w += stride) {
            float2 xv = x2[w];
            xb2[w] = pack_bf16x2(xv.x, xv.y);
        }
        return;
    }
    // ---- binning specialization
    __shared__ int hcnt[512];
    __shared__ int hbase[512];
    const int chunk0 = blockIdx.x * CHUNK;
    hcnt[tid] = 0;
    __syncthreads();
#pragma unroll 4
    for (int k = 0; k < CHUNK / 512; ++k) {
        int e = chunk0 + tid + k * 512;
        if (e < E) atomicAdd(&hcnt[tgt[e] >> 7], 1);
    }
    __syncthreads();
    {
        int cc = hcnt[tid];
        hbase[tid] = cc ? atomicAdd(&coarseCursor[tid << 4], cc) : 0;  // padded
        hcnt[tid] = 0;  // reuse as rank cursor
    }
    __syncthreads();
#pragma unroll 4
    for (int k = 0; k < CHUNK / 512; ++k) {
        int e = chunk0 + tid + k * 512;
        if (e < E) {
            int t = tgt[e];
            int b = t >> 7;
            int pos = hbase[b] + atomicAdd(&hcnt[b], 1);
            if (pos < CCAP) {
                unsigned q = (unsigned)(fdo[e] * 32767.0f + 0.5f);  // 15-bit
                unsigned long long en = (unsigned long long)(unsigned)src[e]
                                      | ((unsigned long long)(unsigned)(t & 127) << 17)
                                      | ((unsigned long long)q << 24);
                slab[(size_t)b * CCAP + pos] = en;
            }
        }
    }
}

// ---- K2 (A2): one 512-thread block per coarse bucket. Slim counting sort:
// pass1 histogram -> wave0 shfl_up scan of 128 counters -> pass2 scatter into
// LDS eout (slab re-read L2-hot) -> coalesced writeout; emit nodeinfo.
__global__ __launch_bounds__(512) void binA2_kernel(
    const unsigned long long* __restrict__ slab,
    const int* __restrict__ coarseCursor, const float* __restrict__ flux,
    unsigned* __restrict__ epackFine, float4* __restrict__ nodeinfo, int N) {
    const int b = blockIdx.x;
    const int tid = threadIdx.x;
    __shared__ unsigned eout[CCAP];          // 20 KB
    __shared__ int ncnt[CNB];
    __shared__ int nbase[CNB];
    __shared__ int ncur[CNB];
    int cnt = min(coarseCursor[b << 4], CCAP);  // padded cursor
    if (tid < CNB) { ncnt[tid] = 0; ncur[tid] = 0; }
    __syncthreads();
    const unsigned long long* sl = slab + (size_t)b * CCAP;
    for (int i = tid; i < cnt; i += 512)
        atomicAdd(&ncnt[(int)((sl[i] >> 17) & 127)], 1);
    __syncthreads();
    if (tid < 64) {  // wave 0: exclusive scan of 128 counters, 2 per lane
        int c0 = ncnt[2 * tid];
        int c1 = ncnt[2 * tid + 1];
        int s = c0 + c1;
        for (int off = 1; off < 64; off <<= 1) {
            int v = __shfl_up(s, off, 64);
            if (tid >= off) s += v;
        }
        nbase[2 * tid] = s - c1 - c0;
        nbase[2 * tid + 1] = s - c1;
    }
    __syncthreads();
    for (int i = tid; i < cnt; i += 512) {
        unsigned long long e = sl[i];  // L2-hot re-read
        int tl = (int)((e >> 17) & 127);
        int pos = nbase[tl] + atomicAdd(&ncur[tl], 1);
        eout[pos] = (unsigned)(e & 0x1FFFFull)
                  | ((unsigned)((e >> 24) & 0x7FFF) << 17);
    }
    if (tid < CNB) {
        int n = b * CNB + tid;
        if (n < N) {
            int dg = ncnt[tid];
            int rs = b * CCAP + nbase[tid];  // 391*5120 < 2^21
            float4 ni;
            ni.x = rsqrtf((float)(dg + 1));
            ni.y = flux[n];
            ni.z = flux[N + n];
            ni.w = __int_as_float((dg << 21) | rs);
            nodeinfo[n] = ni;
        }
    }
    __syncthreads();
    unsigned* out = epackFine + (size_t)b * CCAP;
    for (int i = tid; i < cnt; i += 512) out[i] = eout[i];
}

// ---- K3: per-target aggregation, wave per node, 8 edges per iteration.
// Launched THREE times (thirds of N) for profiler attribution: with the
// largest part ~21us, the top-5 window must surface binA1/binA2/gemm.
__global__ __launch_bounds__(256) void aggregate_kernel(
    const float4* __restrict__ nodeinfo, const unsigned* __restrict__ epackFine,
    const unsigned* __restrict__ xb2, unsigned* __restrict__ up,
    unsigned* __restrict__ vp, int N, int nodeBase, int nodeEnd) {
    const int lane = threadIdx.x & 63;
    const int wslot = threadIdx.x >> 6;
    const int node = nodeBase + blockIdx.x * 4 + wslot;
    __shared__ float4 s_e[4][2][64];
    if (node >= nodeEnd) return;
    const int e2 = lane >> 4;       // 0..3
    const int q16 = lane & 15;
    const int g = q16 >> 3;         // batch
    const int p = q16 & 7;          // words 4p..4p+3 = channels 8p..8p+7
    float4 ni = nodeinfo[node];
    const unsigned wbits = (unsigned)__float_as_int(ni.w);
    const int start = (int)(wbits & 0x1FFFFFu);
    const int end = start + (int)(wbits >> 21);
    const float dt = ni.x, f0t = ni.y, f1t = ni.z;
    const char* xbg = (const char*)xb2 + (size_t)g * N * 128 + p * 16;
    float au[8] = {0, 0, 0, 0, 0, 0, 0, 0};
    float av[8] = {0, 0, 0, 0, 0, 0, 0, 0};
    for (int base = start; base < end; base += 64) {
        int cnt = min(64, end - base);
        int cntp = (cnt + 7) & ~7;
        if (lane < cnt) {
            unsigned pe = epackFine[base + lane];
            int s = (int)(pe & 0x1FFFFu);
            float fd = (float)(pe >> 17) * (1.0f / 32767.0f);
            float4 nis = nodeinfo[s];
            float nrm = nis.x * dt;
            float p0 = nis.y * f0t;
            float p1 = nis.z * f1t;
            float k0 = 1.0f / (1.0f + __expf(-2.0f * p0));  // (1+tanh)/2
            float k1 = 1.0f / (1.0f + __expf(-2.0f * p1));
            float w = 2.0f * fd - 1.0f;
            float f0 = fmaf(k0, w, 1.0f - fd);
            float f1 = fmaf(k1, w, 1.0f - fd);
            float soff = __int_as_float(s << 7);
            s_e[wslot][0][lane] = make_float4(soff, nrm * (1.0f - f0), nrm * f0, 0.f);
            s_e[wslot][1][lane] = make_float4(soff, nrm * (1.0f - f1), nrm * f1, 0.f);
        } else if (lane < cntp) {
            float4 z = make_float4(0.f, 0.f, 0.f, 0.f);
            s_e[wslot][0][lane] = z;
            s_e[wslot][1][lane] = z;
        }
        // wave-private LDS: in-wave write->read ordering via lgkmcnt only
        float4 rA = s_e[wslot][g][e2];
        float4 rB = s_e[wslot][g][4 + e2];
        uint4 xA = *(const uint4*)(xbg + __float_as_int(rA.x));
        uint4 xB = *(const uint4*)(xbg + __float_as_int(rB.x));
        for (int j = 8; j < cntp; j += 8) {
            float4 nA = s_e[wslot][g][j + e2];
            float4 nB = s_e[wslot][g][j + 4 + e2];
            uint4 pA = *(const uint4*)(xbg + __float_as_int(nA.x));  // prefetch
            uint4 pB = *(const uint4*)(xbg + __float_as_int(nB.x));  // prefetch
#pragma unroll
            for (int w = 0; w < 4; ++w) {
                unsigned xp = (&xA.x)[w];
                float lo = bflo(xp), hi = bfhi(xp);
                au[2 * w] = fmaf(rA.y, lo, au[2 * w]);
                au[2 * w + 1] = fmaf(rA.y, hi, au[2 * w + 1]);
                av[2 * w] = fmaf(rA.z, lo, av[2 * w]);
                av[2 * w + 1] = fmaf(rA.z, hi, av[2 * w + 1]);
                unsigned xq = (&xB.x)[w];
                float lo2 = bflo(xq), hi2 = bfhi(xq);
                au[2 * w] = fmaf(rB.y, lo2, au[2 * w]);
                au[2 * w + 1] = fmaf(rB.y, hi2, au[2 * w + 1]);
                av[2 * w] = fmaf(rB.z, lo2, av[2 * w]);
                av[2 * w + 1] = fmaf(rB.z, hi2, av[2 * w + 1]);
            }
            xA = pA; rA = nA;
            xB = pB; rB = nB;
        }
#pragma unroll
        for (int w = 0; w < 4; ++w) {
            unsigned xp = (&xA.x)[w];
            float lo = bflo(xp), hi = bfhi(xp);
            au[2 * w] = fmaf(rA.y, lo, au[2 * w]);
            au[2 * w + 1] = fmaf(rA.y, hi, au[2 * w + 1]);
            av[2 * w] = fmaf(rA.z, lo, av[2 * w]);
            av[2 * w + 1] = fmaf(rA.z, hi, av[2 * w + 1]);
            unsigned xq = (&xB.x)[w];
            float lo2 = bflo(xq), hi2 = bfhi(xq);
            au[2 * w] = fmaf(rB.y, lo2, au[2 * w]);
            au[2 * w + 1] = fmaf(rB.y, hi2, au[2 * w + 1]);
            av[2 * w] = fmaf(rB.z, lo2, av[2 * w]);
            av[2 * w + 1] = fmaf(rB.z, hi2, av[2 * w + 1]);
        }
    }
    // merge the 4 edge-subset partials (lanes differing in bits 4,5)
#pragma unroll
    for (int k = 0; k < 8; ++k) {
        au[k] += __shfl_xor(au[k], 16, 64);
        au[k] += __shfl_xor(au[k], 32, 64);
        av[k] += __shfl_xor(av[k], 16, 64);
        av[k] += __shfl_xor(av[k], 32, 64);
    }
    if (e2 == 0) {
        uint4 xs = *(const uint4*)(xbg + ((size_t)node << 7));  // self-loop
        float d2 = dt * dt;
#pragma unroll
        for (int w = 0; w < 4; ++w) {
            unsigned xp = (&xs.x)[w];
            au[2 * w] = fmaf(d2, bflo(xp), au[2 * w]);
            au[2 * w + 1] = fmaf(d2, bfhi(xp), au[2 * w + 1]);
        }
        uint4 uo, vo;
        uo.x = pack_bf16x2(au[0], au[1]);
        uo.y = pack_bf16x2(au[2], au[3]);
        uo.z = pack_bf16x2(au[4], au[5]);
        uo.w = pack_bf16x2(au[6], au[7]);
        vo.x = pack_bf16x2(av[0], av[1]);
        vo.y = pack_bf16x2(av[2], av[3]);
        vo.z = pack_bf16x2(av[4], av[5]);
        vo.w = pack_bf16x2(av[6], av[7]);
        size_t wo = ((size_t)(g * N + node)) * 32 + 4 * p;
        *(uint4*)(up + wo) = uo;
        *(uint4*)(vp + wo) = vo;
    }
}

// ---- K4: MFMA GEMM. out = [u v] @ [Wc;Wd]^T + bias.
__device__ __forceinline__ short8 make_bfrag(const float* __restrict__ row, int off) {
    const float4* p = (const float4*)(row + off);
    float4 lo = p[0], hi = p[1];
    uint4 w;
    w.x = pack_bf16x2(lo.x, lo.y);
    w.y = pack_bf16x2(lo.z, lo.w);
    w.z = pack_bf16x2(hi.x, hi.y);
    w.w = pack_bf16x2(hi.z, hi.w);
    return __builtin_bit_cast(short8, w);
}

__global__ __launch_bounds__(256) void gemm_mfma_kernel(
    const unsigned* __restrict__ up, const unsigned* __restrict__ vp,
    const float* __restrict__ Wc, const float* __restrict__ Wd,
    const float* __restrict__ bias, float* __restrict__ out, int ntiles) {
    const int lane = threadIdx.x & 63;
    const int nl = lane & 15;
    const int quad = lane >> 4;
    const int wave = blockIdx.x * 4 + (threadIdx.x >> 6);
    const int nwaves = gridDim.x * 4;

    short8 bf[4][4];
    float bt[4];
#pragma unroll
    for (int t = 0; t < 4; ++t) {
        int n = 16 * t + nl;
        const float* wcr = Wc + n * 64;
        const float* wdr = Wd + n * 64;
        bf[0][t] = make_bfrag(wcr, quad * 8);
        bf[1][t] = make_bfrag(wcr, 32 + quad * 8);
        bf[2][t] = make_bfrag(wdr, quad * 8);
        bf[3][t] = make_bfrag(wdr, 32 + quad * 8);
        bt[t] = bias[n];
    }

    for (int tile = wave; tile < ntiles; tile += nwaves) {
        int row = tile * 16 + nl;
        const uint4* ur = (const uint4*)(up + (size_t)row * 32);
        const uint4* vr = (const uint4*)(vp + (size_t)row * 32);
        short8 a0 = __builtin_bit_cast(short8, ur[quad]);
        short8 a1 = __builtin_bit_cast(short8, ur[4 + quad]);
        short8 a2 = __builtin_bit_cast(short8, vr[quad]);
        short8 a3 = __builtin_bit_cast(short8, vr[4 + quad]);
        f32x4 acc[4];
#pragma unroll
        for (int t = 0; t < 4; ++t) {
            f32x4 z = {0.f, 0.f, 0.f, 0.f};
            acc[t] = __builtin_amdgcn_mfma_f32_16x16x32_bf16(a0, bf[0][t], z, 0, 0, 0);
            acc[t] = __builtin_amdgcn_mfma_f32_16x16x32_bf16(a1, bf[1][t], acc[t], 0, 0, 0);
            acc[t] = __builtin_amdgcn_mfma_f32_16x16x32_bf16(a2, bf[2][t], acc[t], 0, 0, 0);
            acc[t] = __builtin_amdgcn_mfma_f32_16x16x32_bf16(a3, bf[3][t], acc[t], 0, 0, 0);
        }
        float* ob = out + ((size_t)(tile * 16 + quad * 4) << 6);
#pragma unroll
        for (int t = 0; t < 4; ++t) {
            int col = 16 * t + nl;
#pragma unroll
            for (int r = 0; r < 4; ++r)
                ob[(r << 6) + col] = acc[t][r] + bt[t];
        }
    }
}

extern "C" void kernel_launch(void* const* d_in, const int* in_sizes, int n_in,
                              void* d_out, int out_size, void* d_ws, size_t ws_size,
                              hipStream_t stream) {
    const float* x = (const float*)d_in[0];
    const int* ei = (const int*)d_in[1];
    const float* fdo = (const float*)d_in[2];
    const float* flux = (const float*)d_in[3];
    const float* Wc = (const float*)d_in[4];
    const float* Wd = (const float*)d_in[5];
    const float* bias = (const float*)d_in[6];
    float* out = (float*)d_out;

    const int E = in_sizes[2];
    const int BN = in_sizes[3];
    const int N = BN / 2;
    const int ncoarse = (N + CNB - 1) / CNB;  // 391

    auto align = [](size_t o) { return (o + 255) & ~(size_t)255; };
    char* ws = (char*)d_ws;
    size_t o = 0;
    int* coarseCursor = (int*)(ws + o);            o = align(o + (size_t)ncoarse * CPAD * 4);
    float4* nodeinfo = (float4*)(ws + o);          o = align(o + (size_t)N * 16);
    unsigned long long* slab = (unsigned long long*)(ws + o);
    unsigned* up = (unsigned*)slab;                // overlay: slab dead after A2
    o = align(o + (size_t)ncoarse * CCAP * 8);     // 16.0 MB >= up 12.8 MB
    unsigned* epackFine = (unsigned*)(ws + o);     o = align(o + (size_t)ncoarse * CCAP * 4);
    unsigned* xb2 = (unsigned*)(ws + o);           o = align(o + (size_t)BN * 32 * 4);
    unsigned* vp = (unsigned*)(ws + o);            o += (size_t)BN * 32 * 4;
    // total ~50.4 MB

    const int* srcp = ei;
    const int* tgtp = ei + E;

    const int nBin = (E + CHUNK - 1) / CHUNK;  // 391
    const int T1 = ((N / 3) + 3) & ~3;         // ~16668, multiple of 4
    const int T2 = ((2 * N / 3) + 3) & ~3;     // ~33336, multiple of 4

    hipMemsetAsync(coarseCursor, 0, (size_t)ncoarse * CPAD * 4, stream);
    binA1_convert_kernel<<<nBin + NCV, 512, 0, stream>>>(
        srcp, tgtp, fdo, coarseCursor, slab, E, ncoarse, nBin, x, xb2, BN * 32);
    binA2_kernel<<<ncoarse, 512, 0, stream>>>(slab, coarseCursor, flux,
                                              epackFine, nodeinfo, N);
    aggregate_kernel<<<T1 / 4, 256, 0, stream>>>(nodeinfo, epackFine, xb2,
                                                 up, vp, N, 0, T1);
    aggregate_kernel<<<(T2 - T1) / 4, 256, 0, stream>>>(nodeinfo, epackFine, xb2,
                                                        up, vp, N, T1, T2);
    aggregate_kernel<<<(N - T2 + 3) / 4, 256, 0, stream>>>(nodeinfo, epackFine, xb2,
                                                           up, vp, N, T2, N);
    gemm_mfma_kernel<<<512, 256, 0, stream>>>(up, vp, Wc, Wd, bias, out, BN / 16);
}

// Round 16
// 206.448 us; speedup vs baseline: 1.0265x; 1.0265x over previous
//
#include <hip/hip_runtime.h>
#include <math.h>

// ReaReaConv via linearity factorization + two-level owner-scatter binning:
//   u[b,t,:] = dis_t^2 * x[b,t,:] + sum_e norm_e*(1-f_be)*x[b,src_e,:]
//   v[b,t,:] =                      sum_e norm_e*   f_be *x[b,src_e,:]
//   out      = bias + [u v] @ [Wc;Wd]^T   (MFMA, M=BN,K=128,N=64)
// Pipeline: K1a{hist+convert} -> K1b{scan} -> K1c{scatter} -> K2{binA2} ->
// K3{aggregate} -> K4{gemm}.   NO GLOBAL ATOMICS in binning:
// R15 attribution showed binA1 stuck at 42us / VALU 4.6% even with padded
// cursors -- each cursor line still serializes 391 cross-XCD RMWs (~100ns
// each = ~40us per-line chain). Replaced with deterministic CSR-of-blocks:
// counts[blk][c] plain stores -> per-bucket 512-wide scan -> bases[blk][c]
// -> scatter with LDS rank. coarseCursor written by scan (memset dropped).
// nodeinfo: {rsqrt(deg+1),flux0,flux1,deg<<21|rowstart}, rowstart<2^21.

constexpr int C = 64;
constexpr int CNB = 128;    // nodes per coarse bucket
constexpr int CCAP = 5120;  // entries per bucket (Poisson mean 4096, +16 sigma)
constexpr int CHUNK = 4096; // edges per binning block (391 blocks)
constexpr int CPAD = 16;    // cursor padding: one cursor per 64B line
constexpr int NCV = 1024;   // dedicated convert blocks in fused K1a

typedef short short8 __attribute__((ext_vector_type(8)));
typedef float f32x4 __attribute__((ext_vector_type(4)));

__device__ __forceinline__ unsigned pack_bf16x2(float a, float b) {
    unsigned ua = __float_as_uint(a);
    ua = (ua + 0x7fffu + ((ua >> 16) & 1u)) >> 16;  // RNE
    unsigned ub = __float_as_uint(b);
    ub = (ub + 0x7fffu + ((ub >> 16) & 1u)) >> 16;
    return ua | (ub << 16);
}
__device__ __forceinline__ float bflo(unsigned p) { return __uint_as_float(p << 16); }
__device__ __forceinline__ float bfhi(unsigned p) { return __uint_as_float(p & 0xffff0000u); }

// ---- K1a: per-block bucket histogram (plain store of count row) + dedicated
// convert blocks (block specialization, proven +9us in R14).
__global__ __launch_bounds__(512) void hist_convert_kernel(
    const int* __restrict__ tgt, int* __restrict__ counts, int E, int nBin,
    const float* __restrict__ x, unsigned* __restrict__ xb2, int nwords) {
    const int tid = threadIdx.x;
    if (blockIdx.x >= nBin) {
        // ---- convert specialization: idle CUs during histogram
        int gid = (blockIdx.x - nBin) * 512 + tid;
        const int stride = NCV * 512;
        const float2* x2 = (const float2*)x;
        for (int w = gid; w < nwords; w += stride) {
            float2 xv = x2[w];
            xb2[w] = pack_bf16x2(xv.x, xv.y);
        }
        return;
    }
    __shared__ int hcnt[512];
    const int chunk0 = blockIdx.x * CHUNK;
    hcnt[tid] = 0;
    __syncthreads();
#pragma unroll 4
    for (int k = 0; k < CHUNK / 512; ++k) {
        int e = chunk0 + tid + k * 512;
        if (e < E) atomicAdd(&hcnt[tgt[e] >> 7], 1);
    }
    __syncthreads();
    counts[blockIdx.x * 512 + tid] = hcnt[tid];  // contiguous row store
}

// ---- K1b: per-bucket exclusive scan over the 391 block-counts.
// One block per bucket; 512-wide Hillis-Steele in LDS. Writes bases[blk][c]
// and the bucket total into the padded coarseCursor slot (binA2-compatible).
__global__ __launch_bounds__(512) void scanbases_kernel(
    const int* __restrict__ counts, int* __restrict__ bases,
    int* __restrict__ coarseCursor, int nBin) {
    const int c = blockIdx.x;  // bucket
    const int tid = threadIdx.x;
    __shared__ int sc[512];
    int v = (tid < nBin) ? counts[tid * 512 + c] : 0;
    sc[tid] = v;
    __syncthreads();
    for (int off = 1; off < 512; off <<= 1) {  // inclusive Hillis-Steele
        int t = (tid >= off) ? sc[tid - off] : 0;
        __syncthreads();
        sc[tid] += t;
        __syncthreads();
    }
    if (tid < nBin) bases[tid * 512 + c] = sc[tid] - v;  // exclusive
    if (tid == 511) coarseCursor[c * CPAD] = sc[511];    // bucket total
}

// ---- K1c: scatter edges into the slab. Deterministic base from K1b; rank
// via LDS cursor. Same entry format / run structure as before.
__global__ __launch_bounds__(512) void scatter_kernel(
    const int* __restrict__ src, const int* __restrict__ tgt,
    const float* __restrict__ fdo, const int* __restrict__ bases,
    unsigned long long* __restrict__ slab, int E) {
    __shared__ int hcnt[512];
    __shared__ int hbase[512];
    const int tid = threadIdx.x;
    const int chunk0 = blockIdx.x * CHUNK;
    hcnt[tid] = 0;
    hbase[tid] = bases[blockIdx.x * 512 + tid];
    __syncthreads();
#pragma unroll 4
    for (int k = 0; k < CHUNK / 512; ++k) {
        int e = chunk0 + tid + k * 512;
        if (e < E) {
            int t = tgt[e];
            int b = t >> 7;
            int pos = hbase[b] + atomicAdd(&hcnt[b], 1);
            if (pos < CCAP) {
                unsigned q = (unsigned)(fdo[e] * 32767.0f + 0.5f);  // 15-bit
                unsigned long long en = (unsigned long long)(unsigned)src[e]
                                      | ((unsigned long long)(unsigned)(t & 127) << 17)
                                      | ((unsigned long long)q << 24);
                slab[(size_t)b * CCAP + pos] = en;
            }
        }
    }
}

// ---- K2 (A2): one 512-thread block per coarse bucket. Slim counting sort:
// pass1 histogram -> wave0 shfl_up scan of 128 counters -> pass2 scatter into
// LDS eout (slab re-read L2-hot) -> coalesced writeout; emit nodeinfo.
__global__ __launch_bounds__(512) void binA2_kernel(
    const unsigned long long* __restrict__ slab,
    const int* __restrict__ coarseCursor, const float* __restrict__ flux,
    unsigned* __restrict__ epackFine, float4* __restrict__ nodeinfo, int N) {
    const int b = blockIdx.x;
    const int tid = threadIdx.x;
    __shared__ unsigned eout[CCAP];          // 20 KB
    __shared__ int ncnt[CNB];
    __shared__ int nbase[CNB];
    __shared__ int ncur[CNB];
    int cnt = min(coarseCursor[b << 4], CCAP);  // padded cursor
    if (tid < CNB) { ncnt[tid] = 0; ncur[tid] = 0; }
    __syncthreads();
    const unsigned long long* sl = slab + (size_t)b * CCAP;
    for (int i = tid; i < cnt; i += 512)
        atomicAdd(&ncnt[(int)((sl[i] >> 17) & 127)], 1);
    __syncthreads();
    if (tid < 64) {  // wave 0: exclusive scan of 128 counters, 2 per lane
        int c0 = ncnt[2 * tid];
        int c1 = ncnt[2 * tid + 1];
        int s = c0 + c1;
        for (int off = 1; off < 64; off <<= 1) {
            int v = __shfl_up(s, off, 64);
            if (tid >= off) s += v;
        }
        nbase[2 * tid] = s - c1 - c0;
        nbase[2 * tid + 1] = s - c1;
    }
    __syncthreads();
    for (int i = tid; i < cnt; i += 512) {
        unsigned long long e = sl[i];  // L2-hot re-read
        int tl = (int)((e >> 17) & 127);
        int pos = nbase[tl] + atomicAdd(&ncur[tl], 1);
        eout[pos] = (unsigned)(e & 0x1FFFFull)
                  | ((unsigned)((e >> 24) & 0x7FFF) << 17);
    }
    if (tid < CNB) {
        int n = b * CNB + tid;
        if (n < N) {
            int dg = ncnt[tid];
            int rs = b * CCAP + nbase[tid];  // 391*5120 < 2^21
            float4 ni;
            ni.x = rsqrtf((float)(dg + 1));
            ni.y = flux[n];
            ni.z = flux[N + n];
            ni.w = __int_as_float((dg << 21) | rs);
            nodeinfo[n] = ni;
        }
    }
    __syncthreads();
    unsigned* out = epackFine + (size_t)b * CCAP;
    for (int i = tid; i < cnt; i += 512) out[i] = eout[i];
}

// ---- K3: per-target aggregation, wave per node, 8 edges per iteration.
// Proven R6/R8 inner loop (2 gathers in flight per lane).
__global__ __launch_bounds__(256) void aggregate_kernel(
    const float4* __restrict__ nodeinfo, const unsigned* __restrict__ epackFine,
    const unsigned* __restrict__ xb2, unsigned* __restrict__ up,
    unsigned* __restrict__ vp, int N) {
    const int lane = threadIdx.x & 63;
    const int wslot = threadIdx.x >> 6;
    const int node = blockIdx.x * 4 + wslot;
    __shared__ float4 s_e[4][2][64];
    if (node >= N) return;
    const int e2 = lane >> 4;       // 0..3
    const int q16 = lane & 15;
    const int g = q16 >> 3;         // batch
    const int p = q16 & 7;          // words 4p..4p+3 = channels 8p..8p+7
    float4 ni = nodeinfo[node];
    const unsigned wbits = (unsigned)__float_as_int(ni.w);
    const int start = (int)(wbits & 0x1FFFFFu);
    const int end = start + (int)(wbits >> 21);
    const float dt = ni.x, f0t = ni.y, f1t = ni.z;
    const char* xbg = (const char*)xb2 + (size_t)g * N * 128 + p * 16;
    float au[8] = {0, 0, 0, 0, 0, 0, 0, 0};
    float av[8] = {0, 0, 0, 0, 0, 0, 0, 0};
    for (int base = start; base < end; base += 64) {
        int cnt = min(64, end - base);
        int cntp = (cnt + 7) & ~7;
        if (lane < cnt) {
            unsigned pe = epackFine[base + lane];
            int s = (int)(pe & 0x1FFFFu);
            float fd = (float)(pe >> 17) * (1.0f / 32767.0f);
            float4 nis = nodeinfo[s];
            float nrm = nis.x * dt;
            float p0 = nis.y * f0t;
            float p1 = nis.z * f1t;
            float k0 = 1.0f / (1.0f + __expf(-2.0f * p0));  // (1+tanh)/2
            float k1 = 1.0f / (1.0f + __expf(-2.0f * p1));
            float w = 2.0f * fd - 1.0f;
            float f0 = fmaf(k0, w, 1.0f - fd);
            float f1 = fmaf(k1, w, 1.0f - fd);
            float soff = __int_as_float(s << 7);
            s_e[wslot][0][lane] = make_float4(soff, nrm * (1.0f - f0), nrm * f0, 0.f);
            s_e[wslot][1][lane] = make_float4(soff, nrm * (1.0f - f1), nrm * f1, 0.f);
        } else if (lane < cntp) {
            float4 z = make_float4(0.f, 0.f, 0.f, 0.f);
            s_e[wslot][0][lane] = z;
            s_e[wslot][1][lane] = z;
        }
        // wave-private LDS: in-wave write->read ordering via lgkmcnt only
        float4 rA = s_e[wslot][g][e2];
        float4 rB = s_e[wslot][g][4 + e2];
        uint4 xA = *(const uint4*)(xbg + __float_as_int(rA.x));
        uint4 xB = *(const uint4*)(xbg + __float_as_int(rB.x));
        for (int j = 8; j < cntp; j += 8) {
            float4 nA = s_e[wslot][g][j + e2];
            float4 nB = s_e[wslot][g][j + 4 + e2];
            uint4 pA = *(const uint4*)(xbg + __float_as_int(nA.x));  // prefetch
            uint4 pB = *(const uint4*)(xbg + __float_as_int(nB.x));  // prefetch
#pragma unroll
            for (int w = 0; w < 4; ++w) {
                unsigned xp = (&xA.x)[w];
                float lo = bflo(xp), hi = bfhi(xp);
                au[2 * w] = fmaf(rA.y, lo, au[2 * w]);
                au[2 * w + 1] = fmaf(rA.y, hi, au[2 * w + 1]);
                av[2 * w] = fmaf(rA.z, lo, av[2 * w]);
                av[2 * w + 1] = fmaf(rA.z, hi, av[2 * w + 1]);
                unsigned xq = (&xB.x)[w];
                float lo2 = bflo(xq), hi2 = bfhi(xq);
                au[2 * w] = fmaf(rB.y, lo2, au[2 * w]);
                au[2 * w + 1] = fmaf(rB.y, hi2, au[2 * w + 1]);
                av[2 * w] = fmaf(rB.z, lo2, av[2 * w]);
                av[2 * w + 1] = fmaf(rB.z, hi2, av[2 * w + 1]);
            }
            xA = pA; rA = nA;
            xB = pB; rB = nB;
        }
#pragma unroll
        for (int w = 0; w < 4; ++w) {
            unsigned xp = (&xA.x)[w];
            float lo = bflo(xp), hi = bfhi(xp);
            au[2 * w] = fmaf(rA.y, lo, au[2 * w]);
            au[2 * w + 1] = fmaf(rA.y, hi, au[2 * w + 1]);
            av[2 * w] = fmaf(rA.z, lo, av[2 * w]);
            av[2 * w + 1] = fmaf(rA.z, hi, av[2 * w + 1]);
            unsigned xq = (&xB.x)[w];
            float lo2 = bflo(xq), hi2 = bfhi(xq);
            au[2 * w] = fmaf(rB.y, lo2, au[2 * w]);
            au[2 * w + 1] = fmaf(rB.y, hi2, au[2 * w + 1]);
            av[2 * w] = fmaf(rB.z, lo2, av[2 * w]);
            av[2 * w + 1] = fmaf(rB.z, hi2, av[2 * w + 1]);
        }
    }
    // merge the 4 edge-subset partials (lanes differing in bits 4,5)
#pragma unroll
    for (int k = 0; k < 8; ++k) {
        au[k] += __shfl_xor(au[k], 16, 64);
        au[k] += __shfl_xor(au[k], 32, 64);
        av[k] += __shfl_xor(av[k], 16, 64);
        av[k] += __shfl_xor(av[k], 32, 64);
    }
    if (e2 == 0) {
        uint4 xs = *(const uint4*)(xbg + ((size_t)node << 7));  // self-loop
        float d2 = dt * dt;
#pragma unroll
        for (int w = 0; w < 4; ++w) {
            unsigned xp = (&xs.x)[w];
            au[2 * w] = fmaf(d2, bflo(xp), au[2 * w]);
            au[2 * w + 1] = fmaf(d2, bfhi(xp), au[2 * w + 1]);
        }
        uint4 uo, vo;
        uo.x = pack_bf16x2(au[0], au[1]);
        uo.y = pack_bf16x2(au[2], au[3]);
        uo.z = pack_bf16x2(au[4], au[5]);
        uo.w = pack_bf16x2(au[6], au[7]);
        vo.x = pack_bf16x2(av[0], av[1]);
        vo.y = pack_bf16x2(av[2], av[3]);
        vo.z = pack_bf16x2(av[4], av[5]);
        vo.w = pack_bf16x2(av[6], av[7]);
        size_t wo = ((size_t)(g * N + node)) * 32 + 4 * p;
        *(uint4*)(up + wo) = uo;
        *(uint4*)(vp + wo) = vo;
    }
}

// ---- K4: MFMA GEMM. out = [u v] @ [Wc;Wd]^T + bias.
__device__ __forceinline__ short8 make_bfrag(const float* __restrict__ row, int off) {
    const float4* p = (const float4*)(row + off);
    float4 lo = p[0], hi = p[1];
    uint4 w;
    w.x = pack_bf16x2(lo.x, lo.y);
    w.y = pack_bf16x2(lo.z, lo.w);
    w.z = pack_bf16x2(hi.x, hi.y);
    w.w = pack_bf16x2(hi.z, hi.w);
    return __builtin_bit_cast(short8, w);
}

__global__ __launch_bounds__(256) void gemm_mfma_kernel(
    const unsigned* __restrict__ up, const unsigned* __restrict__ vp,
    const float* __restrict__ Wc, const float* __restrict__ Wd,
    const float* __restrict__ bias, float* __restrict__ out, int ntiles) {
    const int lane = threadIdx.x & 63;
    const int nl = lane & 15;
    const int quad = lane >> 4;
    const int wave = blockIdx.x * 4 + (threadIdx.x >> 6);
    const int nwaves = gridDim.x * 4;

    short8 bf[4][4];
    float bt[4];
#pragma unroll
    for (int t = 0; t < 4; ++t) {
        int n = 16 * t + nl;
        const float* wcr = Wc + n * 64;
        const float* wdr = Wd + n * 64;
        bf[0][t] = make_bfrag(wcr, quad * 8);
        bf[1][t] = make_bfrag(wcr, 32 + quad * 8);
        bf[2][t] = make_bfrag(wdr, quad * 8);
        bf[3][t] = make_bfrag(wdr, 32 + quad * 8);
        bt[t] = bias[n];
    }

    for (int tile = wave; tile < ntiles; tile += nwaves) {
        int row = tile * 16 + nl;
        const uint4* ur = (const uint4*)(up + (size_t)row * 32);
        const uint4* vr = (const uint4*)(vp + (size_t)row * 32);
        short8 a0 = __builtin_bit_cast(short8, ur[quad]);
        short8 a1 = __builtin_bit_cast(short8, ur[4 + quad]);
        short8 a2 = __builtin_bit_cast(short8, vr[quad]);
        short8 a3 = __builtin_bit_cast(short8, vr[4 + quad]);
        f32x4 acc[4];
#pragma unroll
        for (int t = 0; t < 4; ++t) {
            f32x4 z = {0.f, 0.f, 0.f, 0.f};
            acc[t] = __builtin_amdgcn_mfma_f32_16x16x32_bf16(a0, bf[0][t], z, 0, 0, 0);
            acc[t] = __builtin_amdgcn_mfma_f32_16x16x32_bf16(a1, bf[1][t], acc[t], 0, 0, 0);
            acc[t] = __builtin_amdgcn_mfma_f32_16x16x32_bf16(a2, bf[2][t], acc[t], 0, 0, 0);
            acc[t] = __builtin_amdgcn_mfma_f32_16x16x32_bf16(a3, bf[3][t], acc[t], 0, 0, 0);
        }
        float* ob = out + ((size_t)(tile * 16 + quad * 4) << 6);
#pragma unroll
        for (int t = 0; t < 4; ++t) {
            int col = 16 * t + nl;
#pragma unroll
            for (int r = 0; r < 4; ++r)
                ob[(r << 6) + col] = acc[t][r] + bt[t];
        }
    }
}

extern "C" void kernel_launch(void* const* d_in, const int* in_sizes, int n_in,
                              void* d_out, int out_size, void* d_ws, size_t ws_size,
                              hipStream_t stream) {
    const float* x = (const float*)d_in[0];
    const int* ei = (const int*)d_in[1];
    const float* fdo = (const float*)d_in[2];
    const float* flux = (const float*)d_in[3];
    const float* Wc = (const float*)d_in[4];
    const float* Wd = (const float*)d_in[5];
    const float* bias = (const float*)d_in[6];
    float* out = (float*)d_out;

    const int E = in_sizes[2];
    const int BN = in_sizes[3];
    const int N = BN / 2;
    const int ncoarse = (N + CNB - 1) / CNB;   // 391
    const int nBin = (E + CHUNK - 1) / CHUNK;  // 391

    auto align = [](size_t o) { return (o + 255) & ~(size_t)255; };
    char* ws = (char*)d_ws;
    size_t o = 0;
    int* coarseCursor = (int*)(ws + o);            o = align(o + (size_t)ncoarse * CPAD * 4);
    float4* nodeinfo = (float4*)(ws + o);          o = align(o + (size_t)N * 16);
    unsigned long long* slab = (unsigned long long*)(ws + o);
    unsigned* up = (unsigned*)slab;                // overlay: slab dead after A2
    o = align(o + (size_t)ncoarse * CCAP * 8);     // 16.0 MB >= up 12.8 MB
    unsigned* epackFine = (unsigned*)(ws + o);     o = align(o + (size_t)ncoarse * CCAP * 4);
    unsigned* xb2 = (unsigned*)(ws + o);           o = align(o + (size_t)BN * 32 * 4);
    unsigned* vp = (unsigned*)(ws + o);            o = align(o + (size_t)BN * 32 * 4);
    int* counts = (int*)(ws + o);                  o = align(o + (size_t)nBin * 512 * 4);
    int* bases = (int*)(ws + o);                   o += (size_t)nBin * 512 * 4;
    // total ~52 MB

    const int* srcp = ei;
    const int* tgtp = ei + E;

    hist_convert_kernel<<<nBin + NCV, 512, 0, stream>>>(
        tgtp, counts, E, nBin, x, xb2, BN * 32);
    scanbases_kernel<<<ncoarse, 512, 0, stream>>>(counts, bases, coarseCursor, nBin);
    scatter_kernel<<<nBin, 512, 0, stream>>>(srcp, tgtp, fdo, bases, slab, E);
    binA2_kernel<<<ncoarse, 512, 0, stream>>>(slab, coarseCursor, flux,
                                              epackFine, nodeinfo, N);
    aggregate_kernel<<<(N + 3) / 4, 256, 0, stream>>>(nodeinfo, epackFine, xb2,
                                                      up, vp, N);
    gemm_mfma_kernel<<<512, 256, 0, stream>>>(up, vp, Wc, Wd, bias, out, BN / 16);
}

// Round 17
// 205.598 us; speedup vs baseline: 1.0307x; 1.0041x over previous
//
#include <hip/hip_runtime.h>
#include <math.h>

// ReaReaConv via linearity factorization + two-level owner-scatter binning:
//   u[b,t,:] = dis_t^2 * x[b,t,:] + sum_e norm_e*(1-f_be)*x[b,src_e,:]
//   v[b,t,:] =                      sum_e norm_e*   f_be *x[b,src_e,:]
//   out      = bias + [u v] @ [Wc;Wd]^T   (MFMA, M=BN,K=128,N=64)
// Pipeline: K1a{hist} -> K1b{scan} -> K1c{scatter + convert blocks} ->
// K2{binA2} -> K3{aggregate} -> K4{gemm}.  Atomic-free binning (R16) at
// CHUNK=2048 / 782 blocks: R16 falsified the cursor-atomic theory (atomic
// removal neutral); the surviving suspect is grid starvation (391 blocks =
// 3 waves/SIMD; R7's 196->391 was the only binning lever that helped; R12's
// 2048 retest was confounded by the doubled per-line atomic chain, now gone).
// counts/bases are column-major [c][NBP] so the scan reads/writes coalesced.
// nodeinfo: {rsqrt(deg+1),flux0,flux1,deg<<21|rowstart}, rowstart<2^21.

constexpr int C = 64;
constexpr int CNB = 128;    // nodes per coarse bucket
constexpr int CCAP = 5120;  // entries per bucket (Poisson mean 4096, +16 sigma)
constexpr int CHUNK = 2048; // edges per binning block (782 blocks)
constexpr int NBP = 784;    // padded block count for column-major counts/bases
constexpr int CPAD = 16;    // cursor padding: one cursor per 64B line
constexpr int NCV = 1024;   // dedicated convert blocks in K1c

typedef short short8 __attribute__((ext_vector_type(8)));
typedef float f32x4 __attribute__((ext_vector_type(4)));

__device__ __forceinline__ unsigned pack_bf16x2(float a, float b) {
    unsigned ua = __float_as_uint(a);
    ua = (ua + 0x7fffu + ((ua >> 16) & 1u)) >> 16;  // RNE
    unsigned ub = __float_as_uint(b);
    ub = (ub + 0x7fffu + ((ub >> 16) & 1u)) >> 16;
    return ua | (ub << 16);
}
__device__ __forceinline__ float bflo(unsigned p) { return __uint_as_float(p << 16); }
__device__ __forceinline__ float bfhi(unsigned p) { return __uint_as_float(p & 0xffff0000u); }

// ---- K1a: per-block bucket histogram. counts[c][blk] column-major store.
__global__ __launch_bounds__(512) void hist_kernel(
    const int* __restrict__ tgt, int* __restrict__ counts, int E) {
    __shared__ int hcnt[512];
    const int tid = threadIdx.x;
    const int chunk0 = blockIdx.x * CHUNK;
    hcnt[tid] = 0;
    __syncthreads();
#pragma unroll 4
    for (int k = 0; k < CHUNK / 512; ++k) {
        int e = chunk0 + tid + k * 512;
        if (e < E) atomicAdd(&hcnt[tgt[e] >> 7], 1);
    }
    __syncthreads();
    counts[tid * NBP + blockIdx.x] = hcnt[tid];  // column store (row per bucket)
}

// ---- K1b: per-bucket exclusive scan over 782 block-counts (2 per thread,
// coalesced row read). Writes bases[c][blk] and the bucket total.
__global__ __launch_bounds__(512) void scanbases_kernel(
    const int* __restrict__ counts, int* __restrict__ bases,
    int* __restrict__ coarseCursor, int nBin) {
    const int c = blockIdx.x;  // bucket
    const int tid = threadIdx.x;
    __shared__ int sc[512];
    const int* row = counts + (size_t)c * NBP;
    int a = 0, b = 0;
    if (2 * tid < nBin) a = row[2 * tid];
    if (2 * tid + 1 < nBin) b = row[2 * tid + 1];
    int s = a + b;
    sc[tid] = s;
    __syncthreads();
    for (int off = 1; off < 512; off <<= 1) {  // inclusive over pair-sums
        int t = (tid >= off) ? sc[tid - off] : 0;
        __syncthreads();
        sc[tid] += t;
        __syncthreads();
    }
    int excl = sc[tid] - s;
    int* brow = bases + (size_t)c * NBP;
    if (2 * tid < nBin) brow[2 * tid] = excl;
    if (2 * tid + 1 < nBin) brow[2 * tid + 1] = excl + a;
    if (tid == 511) coarseCursor[c * CPAD] = sc[511];  // bucket total
}

// ---- K1c: scatter edges into the slab (deterministic bases) + dedicated
// convert blocks (block specialization: convert backfills idle CUs).
__global__ __launch_bounds__(512) void scatter_convert_kernel(
    const int* __restrict__ src, const int* __restrict__ tgt,
    const float* __restrict__ fdo, const int* __restrict__ bases,
    unsigned long long* __restrict__ slab, int E, int nBin,
    const float* __restrict__ x, unsigned* __restrict__ xb2, int nwords) {
    const int tid = threadIdx.x;
    if (blockIdx.x >= nBin) {
        int gid = (blockIdx.x - nBin) * 512 + tid;
        const int stride = NCV * 512;
        const float2* x2 = (const float2*)x;
        for (int w = gid; w < nwords; w += stride) {
            float2 xv = x2[w];
            xb2[w] = pack_bf16x2(xv.x, xv.y);
        }
        return;
    }
    __shared__ int hcnt[512];
    __shared__ int hbase[512];
    const int chunk0 = blockIdx.x * CHUNK;
    hcnt[tid] = 0;
    hbase[tid] = bases[(size_t)tid * NBP + blockIdx.x];  // column load
    __syncthreads();
#pragma unroll 4
    for (int k = 0; k < CHUNK / 512; ++k) {
        int e = chunk0 + tid + k * 512;
        if (e < E) {
            int t = tgt[e];
            int b = t >> 7;
            int pos = hbase[b] + atomicAdd(&hcnt[b], 1);
            if (pos < CCAP) {
                unsigned q = (unsigned)(fdo[e] * 32767.0f + 0.5f);  // 15-bit
                unsigned long long en = (unsigned long long)(unsigned)src[e]
                                      | ((unsigned long long)(unsigned)(t & 127) << 17)
                                      | ((unsigned long long)q << 24);
                slab[(size_t)b * CCAP + pos] = en;
            }
        }
    }
}

// ---- K2 (A2): one 512-thread block per coarse bucket. Slim counting sort:
// pass1 histogram -> wave0 shfl_up scan of 128 counters -> pass2 scatter into
// LDS eout (slab re-read L2-hot) -> coalesced writeout; emit nodeinfo.
__global__ __launch_bounds__(512) void binA2_kernel(
    const unsigned long long* __restrict__ slab,
    const int* __restrict__ coarseCursor, const float* __restrict__ flux,
    unsigned* __restrict__ epackFine, float4* __restrict__ nodeinfo, int N) {
    const int b = blockIdx.x;
    const int tid = threadIdx.x;
    __shared__ unsigned eout[CCAP];          // 20 KB
    __shared__ int ncnt[CNB];
    __shared__ int nbase[CNB];
    __shared__ int ncur[CNB];
    int cnt = min(coarseCursor[b << 4], CCAP);  // padded cursor
    if (tid < CNB) { ncnt[tid] = 0; ncur[tid] = 0; }
    __syncthreads();
    const unsigned long long* sl = slab + (size_t)b * CCAP;
    for (int i = tid; i < cnt; i += 512)
        atomicAdd(&ncnt[(int)((sl[i] >> 17) & 127)], 1);
    __syncthreads();
    if (tid < 64) {  // wave 0: exclusive scan of 128 counters, 2 per lane
        int c0 = ncnt[2 * tid];
        int c1 = ncnt[2 * tid + 1];
        int s = c0 + c1;
        for (int off = 1; off < 64; off <<= 1) {
            int v = __shfl_up(s, off, 64);
            if (tid >= off) s += v;
        }
        nbase[2 * tid] = s - c1 - c0;
        nbase[2 * tid + 1] = s - c1;
    }
    __syncthreads();
    for (int i = tid; i < cnt; i += 512) {
        unsigned long long e = sl[i];  // L2-hot re-read
        int tl = (int)((e >> 17) & 127);
        int pos = nbase[tl] + atomicAdd(&ncur[tl], 1);
        eout[pos] = (unsigned)(e & 0x1FFFFull)
                  | ((unsigned)((e >> 24) & 0x7FFF) << 17);
    }
    if (tid < CNB) {
        int n = b * CNB + tid;
        if (n < N) {
            int dg = ncnt[tid];
            int rs = b * CCAP + nbase[tid];  // 391*5120 < 2^21
            float4 ni;
            ni.x = rsqrtf((float)(dg + 1));
            ni.y = flux[n];
            ni.z = flux[N + n];
            ni.w = __int_as_float((dg << 21) | rs);
            nodeinfo[n] = ni;
        }
    }
    __syncthreads();
    unsigned* out = epackFine + (size_t)b * CCAP;
    for (int i = tid; i < cnt; i += 512) out[i] = eout[i];
}

// ---- K3: per-target aggregation, wave per node, 8 edges per iteration.
// Proven R6/R8 inner loop (2 gathers in flight per lane).
__global__ __launch_bounds__(256) void aggregate_kernel(
    const float4* __restrict__ nodeinfo, const unsigned* __restrict__ epackFine,
    const unsigned* __restrict__ xb2, unsigned* __restrict__ up,
    unsigned* __restrict__ vp, int N) {
    const int lane = threadIdx.x & 63;
    const int wslot = threadIdx.x >> 6;
    const int node = blockIdx.x * 4 + wslot;
    __shared__ float4 s_e[4][2][64];
    if (node >= N) return;
    const int e2 = lane >> 4;       // 0..3
    const int q16 = lane & 15;
    const int g = q16 >> 3;         // batch
    const int p = q16 & 7;          // words 4p..4p+3 = channels 8p..8p+7
    float4 ni = nodeinfo[node];
    const unsigned wbits = (unsigned)__float_as_int(ni.w);
    const int start = (int)(wbits & 0x1FFFFFu);
    const int end = start + (int)(wbits >> 21);
    const float dt = ni.x, f0t = ni.y, f1t = ni.z;
    const char* xbg = (const char*)xb2 + (size_t)g * N * 128 + p * 16;
    float au[8] = {0, 0, 0, 0, 0, 0, 0, 0};
    float av[8] = {0, 0, 0, 0, 0, 0, 0, 0};
    for (int base = start; base < end; base += 64) {
        int cnt = min(64, end - base);
        int cntp = (cnt + 7) & ~7;
        if (lane < cnt) {
            unsigned pe = epackFine[base + lane];
            int s = (int)(pe & 0x1FFFFu);
            float fd = (float)(pe >> 17) * (1.0f / 32767.0f);
            float4 nis = nodeinfo[s];
            float nrm = nis.x * dt;
            float p0 = nis.y * f0t;
            float p1 = nis.z * f1t;
            float k0 = 1.0f / (1.0f + __expf(-2.0f * p0));  // (1+tanh)/2
            float k1 = 1.0f / (1.0f + __expf(-2.0f * p1));
            float w = 2.0f * fd - 1.0f;
            float f0 = fmaf(k0, w, 1.0f - fd);
            float f1 = fmaf(k1, w, 1.0f - fd);
            float soff = __int_as_float(s << 7);
            s_e[wslot][0][lane] = make_float4(soff, nrm * (1.0f - f0), nrm * f0, 0.f);
            s_e[wslot][1][lane] = make_float4(soff, nrm * (1.0f - f1), nrm * f1, 0.f);
        } else if (lane < cntp) {
            float4 z = make_float4(0.f, 0.f, 0.f, 0.f);
            s_e[wslot][0][lane] = z;
            s_e[wslot][1][lane] = z;
        }
        // wave-private LDS: in-wave write->read ordering via lgkmcnt only
        float4 rA = s_e[wslot][g][e2];
        float4 rB = s_e[wslot][g][4 + e2];
        uint4 xA = *(const uint4*)(xbg + __float_as_int(rA.x));
        uint4 xB = *(const uint4*)(xbg + __float_as_int(rB.x));
        for (int j = 8; j < cntp; j += 8) {
            float4 nA = s_e[wslot][g][j + e2];
            float4 nB = s_e[wslot][g][j + 4 + e2];
            uint4 pA = *(const uint4*)(xbg + __float_as_int(nA.x));  // prefetch
            uint4 pB = *(const uint4*)(xbg + __float_as_int(nB.x));  // prefetch
#pragma unroll
            for (int w = 0; w < 4; ++w) {
                unsigned xp = (&xA.x)[w];
                float lo = bflo(xp), hi = bfhi(xp);
                au[2 * w] = fmaf(rA.y, lo, au[2 * w]);
                au[2 * w + 1] = fmaf(rA.y, hi, au[2 * w + 1]);
                av[2 * w] = fmaf(rA.z, lo, av[2 * w]);
                av[2 * w + 1] = fmaf(rA.z, hi, av[2 * w + 1]);
                unsigned xq = (&xB.x)[w];
                float lo2 = bflo(xq), hi2 = bfhi(xq);
                au[2 * w] = fmaf(rB.y, lo2, au[2 * w]);
                au[2 * w + 1] = fmaf(rB.y, hi2, au[2 * w + 1]);
                av[2 * w] = fmaf(rB.z, lo2, av[2 * w]);
                av[2 * w + 1] = fmaf(rB.z, hi2, av[2 * w + 1]);
            }
            xA = pA; rA = nA;
            xB = pB; rB = nB;
        }
#pragma unroll
        for (int w = 0; w < 4; ++w) {
            unsigned xp = (&xA.x)[w];
            float lo = bflo(xp), hi = bfhi(xp);
            au[2 * w] = fmaf(rA.y, lo, au[2 * w]);
            au[2 * w + 1] = fmaf(rA.y, hi, au[2 * w + 1]);
            av[2 * w] = fmaf(rA.z, lo, av[2 * w]);
            av[2 * w + 1] = fmaf(rA.z, hi, av[2 * w + 1]);
            unsigned xq = (&xB.x)[w];
            float lo2 = bflo(xq), hi2 = bfhi(xq);
            au[2 * w] = fmaf(rB.y, lo2, au[2 * w]);
            au[2 * w + 1] = fmaf(rB.y, hi2, au[2 * w + 1]);
            av[2 * w] = fmaf(rB.z, lo2, av[2 * w]);
            av[2 * w + 1] = fmaf(rB.z, hi2, av[2 * w + 1]);
        }
    }
    // merge the 4 edge-subset partials (lanes differing in bits 4,5)
#pragma unroll
    for (int k = 0; k < 8; ++k) {
        au[k] += __shfl_xor(au[k], 16, 64);
        au[k] += __shfl_xor(au[k], 32, 64);
        av[k] += __shfl_xor(av[k], 16, 64);
        av[k] += __shfl_xor(av[k], 32, 64);
    }
    if (e2 == 0) {
        uint4 xs = *(const uint4*)(xbg + ((size_t)node << 7));  // self-loop
        float d2 = dt * dt;
#pragma unroll
        for (int w = 0; w < 4; ++w) {
            unsigned xp = (&xs.x)[w];
            au[2 * w] = fmaf(d2, bflo(xp), au[2 * w]);
            au[2 * w + 1] = fmaf(d2, bfhi(xp), au[2 * w + 1]);
        }
        uint4 uo, vo;
        uo.x = pack_bf16x2(au[0], au[1]);
        uo.y = pack_bf16x2(au[2], au[3]);
        uo.z = pack_bf16x2(au[4], au[5]);
        uo.w = pack_bf16x2(au[6], au[7]);
        vo.x = pack_bf16x2(av[0], av[1]);
        vo.y = pack_bf16x2(av[2], av[3]);
        vo.z = pack_bf16x2(av[4], av[5]);
        vo.w = pack_bf16x2(av[6], av[7]);
        size_t wo = ((size_t)(g * N + node)) * 32 + 4 * p;
        *(uint4*)(up + wo) = uo;
        *(uint4*)(vp + wo) = vo;
    }
}

// ---- K4: MFMA GEMM. out = [u v] @ [Wc;Wd]^T + bias.
__device__ __forceinline__ short8 make_bfrag(const float* __restrict__ row, int off) {
    const float4* p = (const float4*)(row + off);
    float4 lo = p[0], hi = p[1];
    uint4 w;
    w.x = pack_bf16x2(lo.x, lo.y);
    w.y = pack_bf16x2(lo.z, lo.w);
    w.z = pack_bf16x2(hi.x, hi.y);
    w.w = pack_bf16x2(hi.z, hi.w);
    return __builtin_bit_cast(short8, w);
}

__global__ __launch_bounds__(256) void gemm_mfma_kernel(
    const unsigned* __restrict__ up, const unsigned* __restrict__ vp,
    const float* __restrict__ Wc, const float* __restrict__ Wd,
    const float* __restrict__ bias, float* __restrict__ out, int ntiles) {
    const int lane = threadIdx.x & 63;
    const int nl = lane & 15;
    const int quad = lane >> 4;
    const int wave = blockIdx.x * 4 + (threadIdx.x >> 6);
    const int nwaves = gridDim.x * 4;

    short8 bf[4][4];
    float bt[4];
#pragma unroll
    for (int t = 0; t < 4; ++t) {
        int n = 16 * t + nl;
        const float* wcr = Wc + n * 64;
        const float* wdr = Wd + n * 64;
        bf[0][t] = make_bfrag(wcr, quad * 8);
        bf[1][t] = make_bfrag(wcr, 32 + quad * 8);
        bf[2][t] = make_bfrag(wdr, quad * 8);
        bf[3][t] = make_bfrag(wdr, 32 + quad * 8);
        bt[t] = bias[n];
    }

    for (int tile = wave; tile < ntiles; tile += nwaves) {
        int row = tile * 16 + nl;
        const uint4* ur = (const uint4*)(up + (size_t)row * 32);
        const uint4* vr = (const uint4*)(vp + (size_t)row * 32);
        short8 a0 = __builtin_bit_cast(short8, ur[quad]);
        short8 a1 = __builtin_bit_cast(short8, ur[4 + quad]);
        short8 a2 = __builtin_bit_cast(short8, vr[quad]);
        short8 a3 = __builtin_bit_cast(short8, vr[4 + quad]);
        f32x4 acc[4];
#pragma unroll
        for (int t = 0; t < 4; ++t) {
            f32x4 z = {0.f, 0.f, 0.f, 0.f};
            acc[t] = __builtin_amdgcn_mfma_f32_16x16x32_bf16(a0, bf[0][t], z, 0, 0, 0);
            acc[t] = __builtin_amdgcn_mfma_f32_16x16x32_bf16(a1, bf[1][t], acc[t], 0, 0, 0);
            acc[t] = __builtin_amdgcn_mfma_f32_16x16x32_bf16(a2, bf[2][t], acc[t], 0, 0, 0);
            acc[t] = __builtin_amdgcn_mfma_f32_16x16x32_bf16(a3, bf[3][t], acc[t], 0, 0, 0);
        }
        float* ob = out + ((size_t)(tile * 16 + quad * 4) << 6);
#pragma unroll
        for (int t = 0; t < 4; ++t) {
            int col = 16 * t + nl;
#pragma unroll
            for (int r = 0; r < 4; ++r)
                ob[(r << 6) + col] = acc[t][r] + bt[t];
        }
    }
}

extern "C" void kernel_launch(void* const* d_in, const int* in_sizes, int n_in,
                              void* d_out, int out_size, void* d_ws, size_t ws_size,
                              hipStream_t stream) {
    const float* x = (const float*)d_in[0];
    const int* ei = (const int*)d_in[1];
    const float* fdo = (const float*)d_in[2];
    const float* flux = (const float*)d_in[3];
    const float* Wc = (const float*)d_in[4];
    const float* Wd = (const float*)d_in[5];
    const float* bias = (const float*)d_in[6];
    float* out = (float*)d_out;

    const int E = in_sizes[2];
    const int BN = in_sizes[3];
    const int N = BN / 2;
    const int ncoarse = (N + CNB - 1) / CNB;   // 391
    const int nBin = (E + CHUNK - 1) / CHUNK;  // 782 (<= NBP)

    auto align = [](size_t o) { return (o + 255) & ~(size_t)255; };
    char* ws = (char*)d_ws;
    size_t o = 0;
    int* coarseCursor = (int*)(ws + o);            o = align(o + (size_t)ncoarse * CPAD * 4);
    float4* nodeinfo = (float4*)(ws + o);          o = align(o + (size_t)N * 16);
    unsigned long long* slab = (unsigned long long*)(ws + o);
    unsigned* up = (unsigned*)slab;                // overlay: slab dead after A2
    o = align(o + (size_t)ncoarse * CCAP * 8);     // 16.0 MB >= up 12.8 MB
    unsigned* epackFine = (unsigned*)(ws + o);     o = align(o + (size_t)ncoarse * CCAP * 4);
    unsigned* xb2 = (unsigned*)(ws + o);           o = align(o + (size_t)BN * 32 * 4);
    unsigned* vp = (unsigned*)(ws + o);            o = align(o + (size_t)BN * 32 * 4);
    int* counts = (int*)(ws + o);                  o = align(o + (size_t)512 * NBP * 4);
    int* bases = (int*)(ws + o);                   o += (size_t)512 * NBP * 4;
    // total ~53 MB

    const int* srcp = ei;
    const int* tgtp = ei + E;

    hist_kernel<<<nBin, 512, 0, stream>>>(tgtp, counts, E);
    scanbases_kernel<<<ncoarse, 512, 0, stream>>>(counts, bases, coarseCursor, nBin);
    scatter_convert_kernel<<<nBin + NCV, 512, 0, stream>>>(
        srcp, tgtp, fdo, bases, slab, E, nBin, x, xb2, BN * 32);
    binA2_kernel<<<ncoarse, 512, 0, stream>>>(slab, coarseCursor, flux,
                                              epackFine, nodeinfo, N);
    aggregate_kernel<<<(N + 3) / 4, 256, 0, stream>>>(nodeinfo, epackFine, xb2,
                                                      up, vp, N);
    gemm_mfma_kernel<<<512, 256, 0, stream>>>(up, vp, Wc, Wd, bias, out, BN / 16);
}

// Round 18
// 202.630 us; speedup vs baseline: 1.0458x; 1.0146x over previous
//
#include <hip/hip_runtime.h>
#include <math.h>

// ReaReaConv via linearity factorization + two-level owner-scatter binning:
//   u[b,t,:] = dis_t^2 * x[b,t,:] + sum_e norm_e*(1-f_be)*x[b,src_e,:]
//   v[b,t,:] =                      sum_e norm_e*   f_be *x[b,src_e,:]
//   out      = bias + [u v] @ [Wc;Wd]^T   (MFMA, M=BN,K=128,N=64)
// Pipeline: memset(padded cursors) -> K1{binA1 + dedicated convert blocks}
// -> K2{binA2} -> K3{aggregate} -> K4{gemm}.  Base = R14 (202.6us best).
// R18 change: VECTORIZED edge/x loads in K1 (int4/float4, 4 edges per
// thread-iter). Five structurally different binning variants all stalled at
// ~42us / VALU 5% / 1.7TB/s -- the shared trait was scalar 4B loads (G13:
// hipcc never auto-vectorizes; 2-2.5x measured cost). LDS atomics, entry
// format, cursor scheme unchanged from R14.
// nodeinfo: {rsqrt(deg+1),flux0,flux1,deg<<21|rowstart}, rowstart<2^21.

constexpr int C = 64;
constexpr int CNB = 128;    // nodes per coarse bucket
constexpr int CCAP = 5120;  // entries per bucket (Poisson mean 4096, +16 sigma)
constexpr int CHUNK = 4096; // edges per binA1 block (391 blocks)
constexpr int CPAD = 16;    // cursor padding: one cursor per 64B line
constexpr int NCV = 1024;   // dedicated convert blocks in fused K1

typedef short short8 __attribute__((ext_vector_type(8)));
typedef float f32x4 __attribute__((ext_vector_type(4)));

__device__ __forceinline__ unsigned pack_bf16x2(float a, float b) {
    unsigned ua = __float_as_uint(a);
    ua = (ua + 0x7fffu + ((ua >> 16) & 1u)) >> 16;  // RNE
    unsigned ub = __float_as_uint(b);
    ub = (ub + 0x7fffu + ((ub >> 16) & 1u)) >> 16;
    return ua | (ub << 16);
}
__device__ __forceinline__ float bflo(unsigned p) { return __uint_as_float(p << 16); }
__device__ __forceinline__ float bfhi(unsigned p) { return __uint_as_float(p & 0xffff0000u); }

// ---- K1: block-specialized fusion.
// blocks [0, nBin): coarse binning into 391 buckets of 128 nodes (per-block
//   LDS histogram -> one padded-cursor atomic per (block,bucket) -> 8B
//   entries in ~10-entry runs). All edge loads int4/float4 (4 edges/iter).
// blocks [nBin, nBin+NCV): x -> packed bf16x2 grid-stride convert (float4).
__global__ __launch_bounds__(512) void binA1_convert_kernel(
    const int* __restrict__ src, const int* __restrict__ tgt,
    const float* __restrict__ fdo, int* __restrict__ coarseCursor,
    unsigned long long* __restrict__ slab, int E, int ncoarse, int nBin,
    const float* __restrict__ x, unsigned* __restrict__ xb2, int nwords) {
    const int tid = threadIdx.x;
    if (blockIdx.x >= nBin) {
        // ---- convert specialization: idle CUs during binning (float4 loads)
        int gid = (blockIdx.x - nBin) * 512 + tid;
        const int stride = NCV * 512;
        const float4* x4 = (const float4*)x;
        uint2* xo = (uint2*)xb2;
        const int n4 = nwords >> 1;  // float4 count (nwords even)
        for (int w = gid; w < n4; w += stride) {
            float4 xv = x4[w];
            uint2 o;
            o.x = pack_bf16x2(xv.x, xv.y);
            o.y = pack_bf16x2(xv.z, xv.w);
            xo[w] = o;
        }
        return;
    }
    // ---- binning specialization (vectorized 4-edge loads)
    __shared__ int hcnt[512];
    __shared__ int hbase[512];
    const int chunk0 = blockIdx.x * CHUNK;
    const int E4 = E >> 2;
    const int base4 = chunk0 >> 2;
    const int4* t4 = (const int4*)tgt;
    const int4* s4 = (const int4*)src;
    const float4* f4 = (const float4*)fdo;
    hcnt[tid] = 0;
    __syncthreads();
#pragma unroll
    for (int k = 0; k < CHUNK / 2048; ++k) {  // 2 vector iterations
        int i4 = base4 + tid + k * 512;
        if (i4 < E4) {
            int4 t = t4[i4];
            atomicAdd(&hcnt[t.x >> 7], 1);
            atomicAdd(&hcnt[t.y >> 7], 1);
            atomicAdd(&hcnt[t.z >> 7], 1);
            atomicAdd(&hcnt[t.w >> 7], 1);
        }
    }
    // scalar tail (E % 4), handled by the last block only
    if (blockIdx.x == nBin - 1 && tid < (E & 3))
        atomicAdd(&hcnt[tgt[(E & ~3) + tid] >> 7], 1);
    __syncthreads();
    {
        int cc = hcnt[tid];
        hbase[tid] = cc ? atomicAdd(&coarseCursor[tid << 4], cc) : 0;  // padded
        hcnt[tid] = 0;  // reuse as rank cursor
    }
    __syncthreads();
#pragma unroll
    for (int k = 0; k < CHUNK / 2048; ++k) {
        int i4 = base4 + tid + k * 512;
        if (i4 < E4) {
            int4 t = t4[i4];
            int4 s = s4[i4];
            float4 f = f4[i4];
#pragma unroll
            for (int j = 0; j < 4; ++j) {
                int tj = (&t.x)[j];
                int b = tj >> 7;
                int pos = hbase[b] + atomicAdd(&hcnt[b], 1);
                if (pos < CCAP) {
                    unsigned q = (unsigned)((&f.x)[j] * 32767.0f + 0.5f);
                    unsigned long long en =
                        (unsigned long long)(unsigned)(&s.x)[j]
                        | ((unsigned long long)(unsigned)(tj & 127) << 17)
                        | ((unsigned long long)q << 24);
                    slab[(size_t)b * CCAP + pos] = en;
                }
            }
        }
    }
    if (blockIdx.x == nBin - 1 && tid < (E & 3)) {
        int e = (E & ~3) + tid;
        int t = tgt[e];
        int b = t >> 7;
        int pos = hbase[b] + atomicAdd(&hcnt[b], 1);
        if (pos < CCAP) {
            unsigned q = (unsigned)(fdo[e] * 32767.0f + 0.5f);
            unsigned long long en = (unsigned long long)(unsigned)src[e]
                                  | ((unsigned long long)(unsigned)(t & 127) << 17)
                                  | ((unsigned long long)q << 24);
            slab[(size_t)b * CCAP + pos] = en;
        }
    }
}

// ---- K2 (A2): one 512-thread block per coarse bucket. Slim counting sort:
// pass1 histogram -> wave0 shfl_up scan of 128 counters -> pass2 scatter into
// LDS eout (slab re-read L2-hot) -> coalesced writeout; emit nodeinfo.
__global__ __launch_bounds__(512) void binA2_kernel(
    const unsigned long long* __restrict__ slab,
    const int* __restrict__ coarseCursor, const float* __restrict__ flux,
    unsigned* __restrict__ epackFine, float4* __restrict__ nodeinfo, int N) {
    const int b = blockIdx.x;
    const int tid = threadIdx.x;
    __shared__ unsigned eout[CCAP];          // 20 KB
    __shared__ int ncnt[CNB];
    __shared__ int nbase[CNB];
    __shared__ int ncur[CNB];
    int cnt = min(coarseCursor[b << 4], CCAP);  // padded cursor
    if (tid < CNB) { ncnt[tid] = 0; ncur[tid] = 0; }
    __syncthreads();
    const unsigned long long* sl = slab + (size_t)b * CCAP;
    for (int i = tid; i < cnt; i += 512)
        atomicAdd(&ncnt[(int)((sl[i] >> 17) & 127)], 1);
    __syncthreads();
    if (tid < 64) {  // wave 0: exclusive scan of 128 counters, 2 per lane
        int c0 = ncnt[2 * tid];
        int c1 = ncnt[2 * tid + 1];
        int s = c0 + c1;
        for (int off = 1; off < 64; off <<= 1) {
            int v = __shfl_up(s, off, 64);
            if (tid >= off) s += v;
        }
        nbase[2 * tid] = s - c1 - c0;
        nbase[2 * tid + 1] = s - c1;
    }
    __syncthreads();
    for (int i = tid; i < cnt; i += 512) {
        unsigned long long e = sl[i];  // L2-hot re-read
        int tl = (int)((e >> 17) & 127);
        int pos = nbase[tl] + atomicAdd(&ncur[tl], 1);
        eout[pos] = (unsigned)(e & 0x1FFFFull)
                  | ((unsigned)((e >> 24) & 0x7FFF) << 17);
    }
    if (tid < CNB) {
        int n = b * CNB + tid;
        if (n < N) {
            int dg = ncnt[tid];
            int rs = b * CCAP + nbase[tid];  // 391*5120 < 2^21
            float4 ni;
            ni.x = rsqrtf((float)(dg + 1));
            ni.y = flux[n];
            ni.z = flux[N + n];
            ni.w = __int_as_float((dg << 21) | rs);
            nodeinfo[n] = ni;
        }
    }
    __syncthreads();
    unsigned* out = epackFine + (size_t)b * CCAP;
    for (int i = tid; i < cnt; i += 512) out[i] = eout[i];
}

// ---- K3: per-target aggregation, wave per node, 8 edges per iteration.
// Proven R6/R8 inner loop (2 gathers in flight per lane).
__global__ __launch_bounds__(256) void aggregate_kernel(
    const float4* __restrict__ nodeinfo, const unsigned* __restrict__ epackFine,
    const unsigned* __restrict__ xb2, unsigned* __restrict__ up,
    unsigned* __restrict__ vp, int N) {
    const int lane = threadIdx.x & 63;
    const int wslot = threadIdx.x >> 6;
    const int node = blockIdx.x * 4 + wslot;
    __shared__ float4 s_e[4][2][64];
    if (node >= N) return;
    const int e2 = lane >> 4;       // 0..3
    const int q16 = lane & 15;
    const int g = q16 >> 3;         // batch
    const int p = q16 & 7;          // words 4p..4p+3 = channels 8p..8p+7
    float4 ni = nodeinfo[node];
    const unsigned wbits = (unsigned)__float_as_int(ni.w);
    const int start = (int)(wbits & 0x1FFFFFu);
    const int end = start + (int)(wbits >> 21);
    const float dt = ni.x, f0t = ni.y, f1t = ni.z;
    const char* xbg = (const char*)xb2 + (size_t)g * N * 128 + p * 16;
    float au[8] = {0, 0, 0, 0, 0, 0, 0, 0};
    float av[8] = {0, 0, 0, 0, 0, 0, 0, 0};
    for (int base = start; base < end; base += 64) {
        int cnt = min(64, end - base);
        int cntp = (cnt + 7) & ~7;
        if (lane < cnt) {
            unsigned pe = epackFine[base + lane];
            int s = (int)(pe & 0x1FFFFu);
            float fd = (float)(pe >> 17) * (1.0f / 32767.0f);
            float4 nis = nodeinfo[s];
            float nrm = nis.x * dt;
            float p0 = nis.y * f0t;
            float p1 = nis.z * f1t;
            float k0 = 1.0f / (1.0f + __expf(-2.0f * p0));  // (1+tanh)/2
            float k1 = 1.0f / (1.0f + __expf(-2.0f * p1));
            float w = 2.0f * fd - 1.0f;
            float f0 = fmaf(k0, w, 1.0f - fd);
            float f1 = fmaf(k1, w, 1.0f - fd);
            float soff = __int_as_float(s << 7);
            s_e[wslot][0][lane] = make_float4(soff, nrm * (1.0f - f0), nrm * f0, 0.f);
            s_e[wslot][1][lane] = make_float4(soff, nrm * (1.0f - f1), nrm * f1, 0.f);
        } else if (lane < cntp) {
            float4 z = make_float4(0.f, 0.f, 0.f, 0.f);
            s_e[wslot][0][lane] = z;
            s_e[wslot][1][lane] = z;
        }
        // wave-private LDS: in-wave write->read ordering via lgkmcnt only
        float4 rA = s_e[wslot][g][e2];
        float4 rB = s_e[wslot][g][4 + e2];
        uint4 xA = *(const uint4*)(xbg + __float_as_int(rA.x));
        uint4 xB = *(const uint4*)(xbg + __float_as_int(rB.x));
        for (int j = 8; j < cntp; j += 8) {
            float4 nA = s_e[wslot][g][j + e2];
            float4 nB = s_e[wslot][g][j + 4 + e2];
            uint4 pA = *(const uint4*)(xbg + __float_as_int(nA.x));  // prefetch
            uint4 pB = *(const uint4*)(xbg + __float_as_int(nB.x));  // prefetch
#pragma unroll
            for (int w = 0; w < 4; ++w) {
                unsigned xp = (&xA.x)[w];
                float lo = bflo(xp), hi = bfhi(xp);
                au[2 * w] = fmaf(rA.y, lo, au[2 * w]);
                au[2 * w + 1] = fmaf(rA.y, hi, au[2 * w + 1]);
                av[2 * w] = fmaf(rA.z, lo, av[2 * w]);
                av[2 * w + 1] = fmaf(rA.z, hi, av[2 * w + 1]);
                unsigned xq = (&xB.x)[w];
                float lo2 = bflo(xq), hi2 = bfhi(xq);
                au[2 * w] = fmaf(rB.y, lo2, au[2 * w]);
                au[2 * w + 1] = fmaf(rB.y, hi2, au[2 * w + 1]);
                av[2 * w] = fmaf(rB.z, lo2, av[2 * w]);
                av[2 * w + 1] = fmaf(rB.z, hi2, av[2 * w + 1]);
            }
            xA = pA; rA = nA;
            xB = pB; rB = nB;
        }
#pragma unroll
        for (int w = 0; w < 4; ++w) {
            unsigned xp = (&xA.x)[w];
            float lo = bflo(xp), hi = bfhi(xp);
            au[2 * w] = fmaf(rA.y, lo, au[2 * w]);
            au[2 * w + 1] = fmaf(rA.y, hi, au[2 * w + 1]);
            av[2 * w] = fmaf(rA.z, lo, av[2 * w]);
            av[2 * w + 1] = fmaf(rA.z, hi, av[2 * w + 1]);
            unsigned xq = (&xB.x)[w];
            float lo2 = bflo(xq), hi2 = bfhi(xq);
            au[2 * w] = fmaf(rB.y, lo2, au[2 * w]);
            au[2 * w + 1] = fmaf(rB.y, hi2, au[2 * w + 1]);
            av[2 * w] = fmaf(rB.z, lo2, av[2 * w]);
            av[2 * w + 1] = fmaf(rB.z, hi2, av[2 * w + 1]);
        }
    }
    // merge the 4 edge-subset partials (lanes differing in bits 4,5)
#pragma unroll
    for (int k = 0; k < 8; ++k) {
        au[k] += __shfl_xor(au[k], 16, 64);
        au[k] += __shfl_xor(au[k], 32, 64);
        av[k] += __shfl_xor(av[k], 16, 64);
        av[k] += __shfl_xor(av[k], 32, 64);
    }
    if (e2 == 0) {
        uint4 xs = *(const uint4*)(xbg + ((size_t)node << 7));  // self-loop
        float d2 = dt * dt;
#pragma unroll
        for (int w = 0; w < 4; ++w) {
            unsigned xp = (&xs.x)[w];
            au[2 * w] = fmaf(d2, bflo(xp), au[2 * w]);
            au[2 * w + 1] = fmaf(d2, bfhi(xp), au[2 * w + 1]);
        }
        uint4 uo, vo;
        uo.x = pack_bf16x2(au[0], au[1]);
        uo.y = pack_bf16x2(au[2], au[3]);
        uo.z = pack_bf16x2(au[4], au[5]);
        uo.w = pack_bf16x2(au[6], au[7]);
        vo.x = pack_bf16x2(av[0], av[1]);
        vo.y = pack_bf16x2(av[2], av[3]);
        vo.z = pack_bf16x2(av[4], av[5]);
        vo.w = pack_bf16x2(av[6], av[7]);
        size_t wo = ((size_t)(g * N + node)) * 32 + 4 * p;
        *(uint4*)(up + wo) = uo;
        *(uint4*)(vp + wo) = vo;
    }
}

// ---- K4: MFMA GEMM. out = [u v] @ [Wc;Wd]^T + bias.
__device__ __forceinline__ short8 make_bfrag(const float* __restrict__ row, int off) {
    const float4* p = (const float4*)(row + off);
    float4 lo = p[0], hi = p[1];
    uint4 w;
    w.x = pack_bf16x2(lo.x, lo.y);
    w.y = pack_bf16x2(lo.z, lo.w);
    w.z = pack_bf16x2(hi.x, hi.y);
    w.w = pack_bf16x2(hi.z, hi.w);
    return __builtin_bit_cast(short8, w);
}

__global__ __launch_bounds__(256) void gemm_mfma_kernel(
    const unsigned* __restrict__ up, const unsigned* __restrict__ vp,
    const float* __restrict__ Wc, const float* __restrict__ Wd,
    const float* __restrict__ bias, float* __restrict__ out, int ntiles) {
    const int lane = threadIdx.x & 63;
    const int nl = lane & 15;
    const int quad = lane >> 4;
    const int wave = blockIdx.x * 4 + (threadIdx.x >> 6);
    const int nwaves = gridDim.x * 4;

    short8 bf[4][4];
    float bt[4];
#pragma unroll
    for (int t = 0; t < 4; ++t) {
        int n = 16 * t + nl;
        const float* wcr = Wc + n * 64;
        const float* wdr = Wd + n * 64;
        bf[0][t] = make_bfrag(wcr, quad * 8);
        bf[1][t] = make_bfrag(wcr, 32 + quad * 8);
        bf[2][t] = make_bfrag(wdr, quad * 8);
        bf[3][t] = make_bfrag(wdr, 32 + quad * 8);
        bt[t] = bias[n];
    }

    for (int tile = wave; tile < ntiles; tile += nwaves) {
        int row = tile * 16 + nl;
        const uint4* ur = (const uint4*)(up + (size_t)row * 32);
        const uint4* vr = (const uint4*)(vp + (size_t)row * 32);
        short8 a0 = __builtin_bit_cast(short8, ur[quad]);
        short8 a1 = __builtin_bit_cast(short8, ur[4 + quad]);
        short8 a2 = __builtin_bit_cast(short8, vr[quad]);
        short8 a3 = __builtin_bit_cast(short8, vr[4 + quad]);
        f32x4 acc[4];
#pragma unroll
        for (int t = 0; t < 4; ++t) {
            f32x4 z = {0.f, 0.f, 0.f, 0.f};
            acc[t] = __builtin_amdgcn_mfma_f32_16x16x32_bf16(a0, bf[0][t], z, 0, 0, 0);
            acc[t] = __builtin_amdgcn_mfma_f32_16x16x32_bf16(a1, bf[1][t], acc[t], 0, 0, 0);
            acc[t] = __builtin_amdgcn_mfma_f32_16x16x32_bf16(a2, bf[2][t], acc[t], 0, 0, 0);
            acc[t] = __builtin_amdgcn_mfma_f32_16x16x32_bf16(a3, bf[3][t], acc[t], 0, 0, 0);
        }
        float* ob = out + ((size_t)(tile * 16 + quad * 4) << 6);
#pragma unroll
        for (int t = 0; t < 4; ++t) {
            int col = 16 * t + nl;
#pragma unroll
            for (int r = 0; r < 4; ++r)
                ob[(r << 6) + col] = acc[t][r] + bt[t];
        }
    }
}

extern "C" void kernel_launch(void* const* d_in, const int* in_sizes, int n_in,
                              void* d_out, int out_size, void* d_ws, size_t ws_size,
                              hipStream_t stream) {
    const float* x = (const float*)d_in[0];
    const int* ei = (const int*)d_in[1];
    const float* fdo = (const float*)d_in[2];
    const float* flux = (const float*)d_in[3];
    const float* Wc = (const float*)d_in[4];
    const float* Wd = (const float*)d_in[5];
    const float* bias = (const float*)d_in[6];
    float* out = (float*)d_out;

    const int E = in_sizes[2];
    const int BN = in_sizes[3];
    const int N = BN / 2;
    const int ncoarse = (N + CNB - 1) / CNB;  // 391

    auto align = [](size_t o) { return (o + 255) & ~(size_t)255; };
    char* ws = (char*)d_ws;
    size_t o = 0;
    int* coarseCursor = (int*)(ws + o);            o = align(o + (size_t)ncoarse * CPAD * 4);
    float4* nodeinfo = (float4*)(ws + o);          o = align(o + (size_t)N * 16);
    unsigned long long* slab = (unsigned long long*)(ws + o);
    unsigned* up = (unsigned*)slab;                // overlay: slab dead after A2
    o = align(o + (size_t)ncoarse * CCAP * 8);     // 16.0 MB >= up 12.8 MB
    unsigned* epackFine = (unsigned*)(ws + o);     o = align(o + (size_t)ncoarse * CCAP * 4);
    unsigned* xb2 = (unsigned*)(ws + o);           o = align(o + (size_t)BN * 32 * 4);
    unsigned* vp = (unsigned*)(ws + o);            o += (size_t)BN * 32 * 4;
    // total ~50.4 MB

    const int* srcp = ei;
    const int* tgtp = ei + E;

    const int nBin = (E + CHUNK - 1) / CHUNK;  // 391

    hipMemsetAsync(coarseCursor, 0, (size_t)ncoarse * CPAD * 4, stream);
    binA1_convert_kernel<<<nBin + NCV, 512, 0, stream>>>(
        srcp, tgtp, fdo, coarseCursor, slab, E, ncoarse, nBin, x, xb2, BN * 32);
    binA2_kernel<<<ncoarse, 512, 0, stream>>>(slab, coarseCursor, flux,
                                              epackFine, nodeinfo, N);
    aggregate_kernel<<<(N + 3) / 4, 256, 0, stream>>>(nodeinfo, epackFine, xb2,
                                                      up, vp, N);
    gemm_mfma_kernel<<<512, 256, 0, stream>>>(up, vp, Wc, Wd, bias, out, BN / 16);
}